// Round 8
// baseline (241.855 us; speedup 1.0000x reference)
//
#include <hip/hip_runtime.h>
#include <math.h>

#define S 1024
#define E 1024
#define H 32
#define KSEL 8
#define D 128
#define HD 4096      // H*D
#define SK 8192      // S*KSEL
#define MAXL 1024
#define CAP 9216     // SK + H*31 padding (per-head padded to 32)
#define ATTN_SCALE 0.08838834764831845f  // 1/sqrt(128)
#define SSTR 36
#define PSTR 40

typedef _Float16 half8 __attribute__((ext_vector_type(8)));
typedef _Float16 half4 __attribute__((ext_vector_type(4)));
typedef float floatx4 __attribute__((ext_vector_type(4)));
typedef float floatx16 __attribute__((ext_vector_type(16)));
typedef float f4 __attribute__((ext_vector_type(4)));

// async 16B global -> LDS (lands at wave-uniform base + lane*16)
#define GLOAD_LDS16(gsrc, ldst) \
    __builtin_amdgcn_global_load_lds( \
        (const __attribute__((address_space(1))) void*)(gsrc), \
        (__attribute__((address_space(3))) void*)(ldst), 16, 0, 0)

// ---------------- prep: convW (blocks 0..4095) + router (blocks 4096..4351) ----------------
__global__ __launch_bounds__(256) void prep_kernel(
    const float* __restrict__ x, const float* __restrict__ Wr,
    const float* __restrict__ Wq, const float* __restrict__ Wk,
    const float* __restrict__ Wv, const float* __restrict__ Wo,
    _Float16* __restrict__ Wqkt, _Float16* __restrict__ Wot,
    int* __restrict__ head_idx, float* __restrict__ head_w,
    float* __restrict__ pbuf, float* __restrict__ entz,
    _Float16* __restrict__ xh)
{
    int bid = blockIdx.x;
    int tid = threadIdx.x;
    if (bid < 4096) {
        // ---- weight transpose+convert ----
        int z = bid >> 10, rem = bid & 1023;
        if (z == 3 && (rem >> 4) >= 16) return;
        const float* W = (z == 0) ? Wq : (z == 1) ? Wk : (z == 2) ? Wv : Wo;
        _Float16* T = (z < 3) ? (Wqkt + (size_t)z * HD * E) : Wot;
        int C = (z < 3) ? HD : 1024;
        int r0 = (rem & 15) * 64, c0 = (rem >> 4) * 64;
        __shared__ float tile[64][65];
        #pragma unroll
        for (int p = 0; p < 4; ++p) {
            int idx = p * 256 + tid;
            int r = idx >> 4, cq = (idx & 15) * 4;
            f4 v = *(const f4*)&W[(size_t)(r0 + r) * C + c0 + cq];
            tile[r][cq] = v.x; tile[r][cq + 1] = v.y; tile[r][cq + 2] = v.z; tile[r][cq + 3] = v.w;
        }
        __syncthreads();
        #pragma unroll
        for (int p = 0; p < 4; ++p) {
            int idx = p * 256 + tid;
            int c = idx >> 4, rq = (idx & 15) * 4;
            half4 o;
            o.x = (_Float16)tile[rq][c];
            o.y = (_Float16)tile[rq + 1][c];
            o.z = (_Float16)tile[rq + 2][c];
            o.w = (_Float16)tile[rq + 3][c];
            *(half4*)&T[(size_t)(c0 + c) * 1024 + r0 + rq] = o;
        }
        return;
    }
    // ---- router: one wave per token ----
    int s = (bid - 4096) * 4 + (tid >> 6);
    int lane = tid & 63;
    int h = lane & 31, half = lane >> 5;
    const float* xr = x + (size_t)s * E + half * 512;
    const float* wr = Wr + (size_t)(half * 512) * H + h;
    float a0 = 0.f, a1 = 0.f, a2 = 0.f, a3 = 0.f;   // 4 chains: hide FMA latency
    #pragma unroll 4
    for (int e = 0; e < 512; e += 4) {
        a0 += xr[e]     * wr[e * H];
        a1 += xr[e + 1] * wr[(e + 1) * H];
        a2 += xr[e + 2] * wr[(e + 2) * H];
        a3 += xr[e + 3] * wr[(e + 3) * H];
    }
    float acc = (a0 + a1) + (a2 + a3);
    acc += __shfl_xor(acc, 32, 64);       // combine halves; all 64 lanes: logit[h]
    float logit = acc;
    float m = logit;
    #pragma unroll
    for (int off = 16; off; off >>= 1) m = fmaxf(m, __shfl_xor(m, off, 64));
    float ex = expf(logit - m);
    float Z = ex;
    #pragma unroll
    for (int off = 16; off; off >>= 1) Z += __shfl_xor(Z, off, 64);
    float p = ex / Z;
    float es = p * logf(p + 1e-8f);
    #pragma unroll
    for (int off = 16; off; off >>= 1) es += __shfl_xor(es, off, 64);
    float lse = m + logf(Z);
    // top-8: butterfly max with tie -> lowest index (jax.lax.top_k semantics)
    float lv = logit;
    float tv[KSEL]; int ti[KSEL];
    #pragma unroll
    for (int j = 0; j < KSEL; ++j) {
        float bv = lv; int bi = h;
        #pragma unroll
        for (int off = 16; off; off >>= 1) {
            float ov = __shfl_xor(bv, off, 64);
            int oi = __shfl_xor(bi, off, 64);
            if (ov > bv || (ov == bv && oi < bi)) { bv = ov; bi = oi; }
        }
        tv[j] = bv; ti[j] = bi;
        if (h == bi) lv = -INFINITY;
    }
    float Z2 = 0.f;
    #pragma unroll
    for (int j = 0; j < KSEL; ++j) Z2 += expf(tv[j] - tv[0]);
    if (lane < 32) pbuf[s * 32 + lane] = p;
    if (lane == 0) {
        entz[s * 2]     = es;
        entz[s * 2 + 1] = lse * lse;
        #pragma unroll
        for (int j = 0; j < KSEL; ++j) {
            head_idx[s * KSEL + j] = ti[j];
            head_w[s * KSEL + j]   = expf(tv[j] - tv[0]) / Z2;
        }
    }
    // fused x -> fp16 for this token's row (wave-cooperative, coalesced)
    const float* xrow = x + (size_t)s * E;
    _Float16* xhrow = xh + (size_t)s * E;
    #pragma unroll
    for (int t = 0; t < 4; ++t) {
        int e = t * 256 + lane * 4;
        f4 v = *(const f4*)&xrow[e];
        half4 o;
        o.x = (_Float16)v.x; o.y = (_Float16)v.y; o.z = (_Float16)v.z; o.w = (_Float16)v.w;
        *(half4*)&xhrow[e] = o;
    }
}

// ---------------- per-head ordered lists (ballot scan) + fused aux-loss block ----------------
__global__ __launch_bounds__(256) void order_kernel(
    const int* __restrict__ head_idx, const int* __restrict__ head_counts,
    int* __restrict__ order, int* __restrict__ hlen, float* __restrict__ out_counts,
    const float* __restrict__ pbuf, const float* __restrict__ entz,
    float* __restrict__ out_aux)
{
    int h = blockIdx.x, tid = threadIdx.x;
    if (h == H) {
        // ---- aux loss reduction (block 32) ----
        int hh = tid & 31, grp = tid >> 5;
        __shared__ float red[256], red2[256];
        __shared__ float psum[32];
        __shared__ int hist[32];
        if (tid < 32) hist[tid] = 0;
        float ps = 0.f;
        for (int s = grp; s < S; s += 8) ps += pbuf[s * 32 + hh];
        red[tid] = ps;
        float es = 0.f, zs = 0.f;
        for (int s = tid; s < S; s += 256) { es += entz[s * 2]; zs += entz[s * 2 + 1]; }
        red2[tid] = es;
        __syncthreads();
        if (grp == 0) {
            float v = 0.f;
            #pragma unroll
            for (int j = 0; j < 8; ++j) v += red[j * 32 + hh];
            psum[hh] = v;
        }
        __syncthreads();
        red[tid] = zs;
        for (int s = tid; s < S; s += 256)
            atomicAdd(&hist[head_idx[s * KSEL]], 1);
        __syncthreads();
        for (int stp = 128; stp; stp >>= 1) {
            if (tid < stp) { red[tid] += red[tid + stp]; red2[tid] += red2[tid + stp]; }
            __syncthreads();
        }
        if (tid == 0) {
            float bal = 0.f;
            for (int j = 0; j < H; ++j)
                bal += ((float)hist[j] / (float)S) * (psum[j] / (float)S);
            bal *= (float)H;
            float ent_loss = red2[0] / (float)S;
            float z = red[0] / (float)S * 0.01f;
            out_aux[0] = 0.01f * bal + 0.01f * ent_loss + z;
        }
        return;
    }
    int wave = tid >> 6, lane = tid & 63;
    __shared__ int wtot[4];
    int base = 0;
    int hc = head_counts[h];
    int v = head_idx[tid];
    for (int c0 = 0; c0 < SK; c0 += 256) {
        int vn = (c0 + 256 < SK) ? head_idx[c0 + 256 + tid] : 0;  // prefetch next chunk
        bool pred = (v == h);
        unsigned long long mask = __ballot(pred);
        int within = __popcll(mask & ((1ull << lane) - 1ull));
        if (lane == 0) wtot[wave] = __popcll(mask);
        __syncthreads();
        int pre = 0, tot = 0;
        #pragma unroll
        for (int w = 0; w < 4; ++w) { int t = wtot[w]; if (w < wave) pre += t; tot += t; }
        if (pred) order[h * MAXL + base + pre + within] = c0 + tid;
        base += tot;
        __syncthreads();
        v = vn;
    }
    if (tid == 0) {
        hlen[h] = base;
        out_counts[h] = (float)(hc + base);
    }
}

// ---------------- gathered QKV projection: B-only LDS dbuf, A direct-to-reg + fused RoPE ----------------
__global__ __launch_bounds__(256) void qkv_mfma(
    const _Float16* __restrict__ xh, const _Float16* __restrict__ Wt,
    const int* __restrict__ order, const int* __restrict__ hlen,
    const int* __restrict__ head_counts,
    _Float16* __restrict__ qh, _Float16* __restrict__ kh, _Float16* __restrict__ vT)
{
    int xid = blockIdx.x;
    int qkv = xid >> 5, h = xid & 31;
    int rt = blockIdx.y;
    int len = hlen[h];
    int row0 = rt * 64;
    if (row0 >= len) return;
    int hb = 0;
    for (int i = 0; i < h; ++i) hb += (hlen[i] + 31) & ~31;   // inline hstart prefix
    int lenp = (len + 31) & ~31;
    int tid = threadIdx.x, wave = tid >> 6, lane = tid & 63;
    int wm = wave >> 1, wn = wave & 1;
    int l32 = lane & 31, g = lane >> 5;

    __shared__ _Float16 Bs[2][128 * 64];

    // A operand: xh rows are k-contiguous == 32x32x16 A-frag layout -> registers, no LDS
    int arow_g = row0 + wm * 32 + l32;
    int tok = (arow_g < len) ? (order[h * MAXL + arow_g] >> 3) : 0;
    const _Float16* aptr = xh + (size_t)tok * E;

    const _Float16* Wb = Wt + (size_t)((qkv * H + h) * D) * E;

    auto stageB = [&](int buf, int k0) {
        #pragma unroll
        for (int it = 0; it < 4; ++it) {
            int f = it * 256 + tid;
            int row = f >> 3, c = f & 7;
            int sc = c ^ (row & 7);
            const _Float16* src = Wb + (size_t)row * E + k0 + sc * 8;
            GLOAD_LDS16(src, &Bs[buf][f * 8]);
        }
    };

    floatx16 acc[2] = {};
    half8 a_cur[4], a_nxt[4];
    #pragma unroll
    for (int ks = 0; ks < 4; ++ks)
        a_cur[ks] = *(const half8*)(aptr + ks * 16 + g * 8);

    auto compute = [&](int buf, half8* a) {
        #pragma unroll
        for (int ks = 0; ks < 4; ++ks) {
            int wchunk = ks * 2 + g;
            #pragma unroll
            for (int nf = 0; nf < 2; ++nf) {
                int brow = wn * 64 + nf * 32 + l32;
                half8 bf = *(const half8*)&Bs[buf][brow * 64 + (wchunk ^ (brow & 7)) * 8];
                acc[nf] = __builtin_amdgcn_mfma_f32_32x32x16_f16(a[ks], bf, acc[nf], 0, 0, 0);
            }
        }
    };

    stageB(0, 0);
    __syncthreads();
    int buf = 0;
    for (int k0 = 64; k0 < E; k0 += 64) {
        stageB(buf ^ 1, k0);
        #pragma unroll
        for (int ks = 0; ks < 4; ++ks)
            a_nxt[ks] = *(const half8*)(aptr + k0 + ks * 16 + g * 8);
        compute(buf, a_cur);
        __syncthreads();
        buf ^= 1;
        #pragma unroll
        for (int ks = 0; ks < 4; ++ks) a_cur[ks] = a_nxt[ks];
    }
    compute(buf, a_cur);

    if (qkv < 2) {
        // fused RoPE: round-trip acc through LDS (reuse Bs as 64x128 fp32 scratch)
        _Float16* dst = (qkv == 0) ? qh : kh;
        float* scr = (float*)&Bs[0][0];
        __syncthreads();   // all waves done reading Bs
        #pragma unroll
        for (int nf = 0; nf < 2; ++nf) {
            int col = wn * 64 + nf * 32 + l32;
            #pragma unroll
            for (int reg = 0; reg < 16; ++reg) {
                int rl = wm * 32 + (reg & 3) + 8 * (reg >> 2) + 4 * g;
                scr[rl * 128 + col] = acc[nf][reg];
            }
        }
        __syncthreads();
        int hc = head_counts[h];
        #pragma unroll
        for (int pass = 0; pass < 16; ++pass) {
            int idx = pass * 256 + tid;
            int r = idx >> 6, d2 = idx & 63;
            int slot = row0 + r;
            if (slot < len) {
                float v1 = scr[r * 128 + d2], v2 = scr[r * 128 + 64 + d2];
                int p = slot + hc;
                p = p < 0 ? 0 : (p > 8191 ? 8191 : p);
                float inv = exp2f((float)d2 * -0.20762050f);  // 10000^(-d2/64)
                float ang = (float)p * inv;
                float cs = cosf(ang), sn = sinf(ang);
                _Float16* dp = dst + ((size_t)hb + slot) * D;
                dp[d2]      = (_Float16)(v1 * cs - v2 * sn);
                dp[d2 + 64] = (_Float16)(v2 * cs + v1 * sn);
            }
        }
    } else {
        #pragma unroll
        for (int nf = 0; nf < 2; ++nf) {
            int col = wn * 64 + nf * 32 + l32;
            #pragma unroll
            for (int q4 = 0; q4 < 4; ++q4) {
                int slot0 = row0 + wm * 32 + 8 * q4 + 4 * g;
                _Float16* vp = vT + (size_t)hb * D + (size_t)col * lenp + slot0;
                if (slot0 + 3 < len) {
                    half4 o;
                    o.x = (_Float16)acc[nf][q4 * 4 + 0];
                    o.y = (_Float16)acc[nf][q4 * 4 + 1];
                    o.z = (_Float16)acc[nf][q4 * 4 + 2];
                    o.w = (_Float16)acc[nf][q4 * 4 + 3];
                    *(half4*)vp = o;
                } else {
                    #pragma unroll
                    for (int r2 = 0; r2 < 4; ++r2)
                        if (slot0 + r2 < len) vp[r2] = (_Float16)acc[nf][q4 * 4 + r2];
                }
            }
        }
    }
}

// ---------------- per-head causal flash attention: 2-wave split-K, MFMA 32x32x16 ----------------
__global__ __launch_bounds__(128) void attn_mfma(
    const _Float16* __restrict__ qh, const _Float16* __restrict__ kh,
    const _Float16* __restrict__ vT,
    const int* __restrict__ order, const int* __restrict__ hlen,
    const float* __restrict__ head_w, _Float16* __restrict__ ao)
{
    int h = blockIdx.x >> 5, qt = blockIdx.x & 31;
    int len = hlen[h];
    int row0 = qt * 32;
    if (row0 >= len) return;
    int hb = 0;
    for (int i = 0; i < h; ++i) hb += (hlen[i] + 31) & ~31;
    int lenp = (len + 31) & ~31;
    int tid = threadIdx.x;
    int w = tid >> 6, lane = tid & 63;
    int l32 = lane & 31, g = lane >> 5;
    int srow = lane >> 1, shalf = lane & 1;

    __shared__ float Sld[2][32 * SSTR];
    __shared__ _Float16 Pld[2][32 * PSTR];
    __shared__ float alphaLd[2][32];
    __shared__ float mlLd[32][4];     // m0,l0,m1,l1
    __shared__ float facLd[32][3];    // f1, hw/l*, f0
    __shared__ int flatLd[32];
    __shared__ float Obuf[32][128];

    if (tid < 32) {
        int r = row0 + tid;
        flatLd[tid] = (r < len) ? order[h * MAXL + r] : -1;
    }

    const _Float16* qrow = qh + ((size_t)hb + row0 + l32) * D;
    half8 qf[8];
    #pragma unroll
    for (int t = 0; t < 8; ++t) qf[t] = *(const half8*)(qrow + t * 16 + g * 8);

    floatx16 O[4] = {};
    float m_run = -INFINITY, l_run = 0.f;

    if (w <= qt) {
        half8 kf[8], kfn[8], vv[8];
        {
            const _Float16* krow = kh + ((size_t)hb + w * 32 + l32) * D;
            #pragma unroll
            for (int t = 0; t < 8; ++t) kf[t] = *(const half8*)(krow + t * 16 + g * 8);
        }
        for (int kt = w; kt <= qt; kt += 2) {
            int col0 = kt * 32;
            floatx16 Sc = {};
            #pragma unroll
            for (int t = 0; t < 8; ++t)
                Sc = __builtin_amdgcn_mfma_f32_32x32x16_f16(qf[t], kf[t], Sc, 0, 0, 0);
            // prefetch this tile's V and next K (overlap with softmax)
            #pragma unroll
            for (int nt = 0; nt < 4; ++nt) {
                const _Float16* vp = vT + (size_t)hb * D + (size_t)(nt * 32 + l32) * lenp + col0;
                vv[nt * 2]     = *(const half8*)(vp + g * 8);
                vv[nt * 2 + 1] = *(const half8*)(vp + 16 + g * 8);
            }
            if (kt + 2 <= qt) {
                const _Float16* krow = kh + ((size_t)hb + col0 + 64 + l32) * D;
                #pragma unroll
                for (int t = 0; t < 8; ++t) kfn[t] = *(const half8*)(krow + t * 16 + g * 8);
            }
            bool diag = (kt == qt);
            #pragma unroll
            for (int reg = 0; reg < 16; ++reg) {
                int row = (reg & 3) + 8 * (reg >> 2) + 4 * g;
                float s = Sc[reg] * ATTN_SCALE;
                if (diag && l32 > row) s = -1e30f;
                Sld[w][row * SSTR + l32] = s;
            }
            __builtin_amdgcn_wave_barrier();
            const float* sp = &Sld[w][srow * SSTR + shalf * 16];
            float va[16];
            *(f4*)(va)      = *(const f4*)(sp);
            *(f4*)(va + 4)  = *(const f4*)(sp + 4);
            *(f4*)(va + 8)  = *(const f4*)(sp + 8);
            *(f4*)(va + 12) = *(const f4*)(sp + 12);
            float mt_ = va[0];
            #pragma unroll
            for (int j = 1; j < 16; ++j) mt_ = fmaxf(mt_, va[j]);
            mt_ = fmaxf(mt_, __shfl_xor(mt_, 1, 64));
            float m_new = fmaxf(m_run, mt_);
            float alpha = __expf(m_run - m_new);
            float p[16], tsum = 0.f;
            #pragma unroll
            for (int j = 0; j < 16; ++j) { p[j] = __expf(va[j] - m_new); tsum += p[j]; }
            tsum += __shfl_xor(tsum, 1, 64);
            l_run = l_run * alpha + tsum;
            m_run = m_new;
            half8 ph0, ph1;
            #pragma unroll
            for (int j = 0; j < 8; ++j) { ph0[j] = (_Float16)p[j]; ph1[j] = (_Float16)p[j + 8]; }
            *(half8*)&Pld[w][srow * PSTR + shalf * 16]     = ph0;
            *(half8*)&Pld[w][srow * PSTR + shalf * 16 + 8] = ph1;
            if (shalf == 0) alphaLd[w][srow] = alpha;
            __builtin_amdgcn_wave_barrier();
            f4 al[4];
            #pragma unroll
            for (int qq = 0; qq < 4; ++qq) al[qq] = *(const f4*)&alphaLd[w][4 * g + 8 * qq];
            #pragma unroll
            for (int reg = 0; reg < 16; ++reg) {
                float av = al[reg >> 2][reg & 3];
                O[0][reg] *= av; O[1][reg] *= av; O[2][reg] *= av; O[3][reg] *= av;
            }
            half8 pf0 = *(const half8*)&Pld[w][l32 * PSTR + g * 8];
            half8 pf1 = *(const half8*)&Pld[w][l32 * PSTR + 16 + g * 8];
            #pragma unroll
            for (int nt = 0; nt < 4; ++nt) {
                O[nt] = __builtin_amdgcn_mfma_f32_32x32x16_f16(pf0, vv[nt * 2],     O[nt], 0, 0, 0);
                O[nt] = __builtin_amdgcn_mfma_f32_32x32x16_f16(pf1, vv[nt * 2 + 1], O[nt], 0, 0, 0);
            }
            __builtin_amdgcn_wave_barrier();
            #pragma unroll
            for (int t = 0; t < 8; ++t) kf[t] = kfn[t];
        }
    }
    // ---- merge the two waves' partial (m, l, O) ----
    if (shalf == 0) { mlLd[srow][w * 2] = m_run; mlLd[srow][w * 2 + 1] = l_run; }
    __syncthreads();
    if (tid < 32) {
        float m0 = mlLd[tid][0], l0 = mlLd[tid][1];
        float m1 = mlLd[tid][2], l1 = mlLd[tid][3];
        float ms = fmaxf(m0, m1);
        float f0 = __expf(m0 - ms), f1 = __expf(m1 - ms);
        float lt = f0 * l0 + f1 * l1;
        int flat = flatLd[tid];
        float hw = (flat >= 0) ? head_w[flat] : 0.f;
        facLd[tid][0] = f1;
        facLd[tid][1] = hw / lt;
        facLd[tid][2] = f0;
    }
    __syncthreads();
    if (w == 1) {
        #pragma unroll
        for (int nt = 0; nt < 4; ++nt) {
            int col = nt * 32 + l32;
            #pragma unroll
            for (int reg = 0; reg < 16; ++reg) {
                int row = (reg & 3) + 8 * (reg >> 2) + 4 * g;
                Obuf[row][col] = O[nt][reg] * facLd[row][0];
            }
        }
    }
    __syncthreads();
    if (w == 0) {
        #pragma unroll
        for (int nt = 0; nt < 4; ++nt) {
            int col = nt * 32 + l32;
            #pragma unroll
            for (int reg = 0; reg < 16; ++reg) {
                int row = (reg & 3) + 8 * (reg >> 2) + 4 * g;
                int flat = flatLd[row];
                if (flat >= 0) {
                    float val = (O[nt][reg] * facLd[row][2] + Obuf[row][col]) * facLd[row][1];
                    ao[(size_t)flat * D + col] = (_Float16)val;
                }
            }
        }
    }
}

// ---------------- output projection: B-only LDS dbuf MFMA GEMM, A direct-to-reg ----------------
__global__ __launch_bounds__(256) void out_mfma(
    const _Float16* __restrict__ A, const _Float16* __restrict__ Bt,
    float* __restrict__ C)
{
    int n0 = blockIdx.x * 64, m0 = blockIdx.y * 64;
    int tid = threadIdx.x, wave = tid >> 6, lane = tid & 63;
    int wm = wave >> 1, wn = wave & 1;
    int l32 = lane & 31, g = lane >> 5;

    __shared__ _Float16 Bs[2][64 * 64];

    const _Float16* aptr = A + (size_t)(m0 + wm * 32 + l32) * 1024;

    auto stageB = [&](int buf, int k0) {
        #pragma unroll
        for (int it = 0; it < 2; ++it) {
            int f = it * 256 + tid;
            int row = f >> 3, c = f & 7;
            int sc = c ^ (row & 7);
            GLOAD_LDS16(Bt + (size_t)(n0 + row) * 1024 + k0 + sc * 8, &Bs[buf][f * 8]);
        }
    };

    floatx16 acc = {};
    int brow = wn * 32 + l32;
    half8 a_cur[4], a_nxt[4];
    #pragma unroll
    for (int ks = 0; ks < 4; ++ks)
        a_cur[ks] = *(const half8*)(aptr + ks * 16 + g * 8);

    auto compute = [&](int buf, half8* a) {
        #pragma unroll
        for (int ks = 0; ks < 4; ++ks) {
            int wchunk = ks * 2 + g;
            half8 bf = *(const half8*)&Bs[buf][brow * 64 + (wchunk ^ (brow & 7)) * 8];
            acc = __builtin_amdgcn_mfma_f32_32x32x16_f16(a[ks], bf, acc, 0, 0, 0);
        }
    };

    stageB(0, 0);
    __syncthreads();
    int buf = 0;
    for (int k0 = 64; k0 < 1024; k0 += 64) {
        stageB(buf ^ 1, k0);
        #pragma unroll
        for (int ks = 0; ks < 4; ++ks)
            a_nxt[ks] = *(const half8*)(aptr + k0 + ks * 16 + g * 8);
        compute(buf, a_cur);
        __syncthreads();
        buf ^= 1;
        #pragma unroll
        for (int ks = 0; ks < 4; ++ks) a_cur[ks] = a_nxt[ks];
    }
    compute(buf, a_cur);

    int col = n0 + wn * 32 + l32;
    #pragma unroll
    for (int reg = 0; reg < 16; ++reg) {
        int row = m0 + wm * 32 + (reg & 3) + 8 * (reg >> 2) + 4 * g;
        C[(size_t)row * 1024 + col] = acc[reg];
    }
}

extern "C" void kernel_launch(void* const* d_in, const int* in_sizes, int n_in,
                              void* d_out, int out_size, void* d_ws, size_t ws_size,
                              hipStream_t stream)
{
    const float* x  = (const float*)d_in[0];
    const float* Wq = (const float*)d_in[1];
    const float* Wk = (const float*)d_in[2];
    const float* Wv = (const float*)d_in[3];
    const float* Wr = (const float*)d_in[4];
    const float* Wo = (const float*)d_in[5];
    const int* head_counts = (const int*)d_in[6];
    float* out = (float*)d_out;

    float* head_w = (float*)d_ws;                 // SK
    float* pbuf   = head_w + SK;                  // S*32
    float* entz   = pbuf + S * 32;                // S*2
    int* head_idx = (int*)(entz + S * 2);         // SK
    int* order    = head_idx + SK;                // H*MAXL
    int* hlen     = order + H * MAXL;             // 32 (pad 64)
    _Float16* xh   = (_Float16*)(hlen + 64);      // S*E
    _Float16* aoh  = xh + (size_t)S * E;          // SK*D
    _Float16* Wqkt = aoh + (size_t)SK * D;        // 3*HD*E
    _Float16* Wot  = Wqkt + (size_t)3 * HD * E;   // 1024*1024
    _Float16* qh   = Wot + (size_t)1024 * 1024;   // CAP*D
    _Float16* kh   = qh + (size_t)CAP * D;        // CAP*D
    _Float16* vT   = kh + (size_t)CAP * D;        // CAP*D

    prep_kernel<<<4096 + 256, 256, 0, stream>>>(x, Wr, Wq, Wk, Wv, Wo, Wqkt, Wot,
                                                head_idx, head_w, pbuf, entz, xh);
    order_kernel<<<H + 1, 256, 0, stream>>>(head_idx, head_counts, order, hlen,
                                            out + (size_t)S * E, pbuf, entz,
                                            out + (size_t)S * E + H);
    qkv_mfma<<<dim3(96, 16), 256, 0, stream>>>(xh, Wqkt, order, hlen, head_counts,
                                               qh, kh, vT);
    attn_mfma<<<H * 32, 128, 0, stream>>>(qh, kh, vT, order, hlen, head_w, aoh);
    out_mfma<<<dim3(16, 16), 256, 0, stream>>>(aoh, Wot, out);
}

// Round 9
// 223.458 us; speedup vs baseline: 1.0823x; 1.0823x over previous
//
#include <hip/hip_runtime.h>
#include <math.h>

#define S 1024
#define E 1024
#define H 32
#define KSEL 8
#define D 128
#define HD 4096      // H*D
#define SK 8192      // S*KSEL
#define MAXL 1024
#define CAP 9216     // SK + H*31 padding (per-head padded to 32)
#define ATTN_SCALE 0.08838834764831845f  // 1/sqrt(128)
#define SSTR 36
#define PSTR 40

typedef _Float16 half8 __attribute__((ext_vector_type(8)));
typedef _Float16 half4 __attribute__((ext_vector_type(4)));
typedef float floatx4 __attribute__((ext_vector_type(4)));
typedef float floatx16 __attribute__((ext_vector_type(16)));
typedef float f4 __attribute__((ext_vector_type(4)));

// async 16B global -> LDS (lands at wave-uniform base + lane*16)
#define GLOAD_LDS16(gsrc, ldst) \
    __builtin_amdgcn_global_load_lds( \
        (const __attribute__((address_space(1))) void*)(gsrc), \
        (__attribute__((address_space(3))) void*)(ldst), 16, 0, 0)

// ---------------- prep: router (blocks 0..255, dispatched FIRST) + convW (256..4351) ----------------
// Router blocks go first so their latency-bound waves overlap with the convW stream;
// tail is then HBM-bound convW, not an idle-machine router chain.
__global__ __launch_bounds__(256) void prep_kernel(
    const float* __restrict__ x, const float* __restrict__ Wr,
    const float* __restrict__ Wq, const float* __restrict__ Wk,
    const float* __restrict__ Wv, const float* __restrict__ Wo,
    _Float16* __restrict__ Wqkt, _Float16* __restrict__ Wot,
    int* __restrict__ head_idx, float* __restrict__ head_w,
    float* __restrict__ pbuf, float* __restrict__ entz,
    _Float16* __restrict__ xh)
{
    int bid = blockIdx.x;
    int tid = threadIdx.x;
    if (bid >= 256) {
        // ---- weight transpose+convert ----
        int cb = bid - 256;
        int z = cb >> 10, rem = cb & 1023;
        if (z == 3 && (rem >> 4) >= 16) return;
        const float* W = (z == 0) ? Wq : (z == 1) ? Wk : (z == 2) ? Wv : Wo;
        _Float16* T = (z < 3) ? (Wqkt + (size_t)z * HD * E) : Wot;
        int C = (z < 3) ? HD : 1024;
        int r0 = (rem & 15) * 64, c0 = (rem >> 4) * 64;
        __shared__ float tile[64][65];
        #pragma unroll
        for (int p = 0; p < 4; ++p) {
            int idx = p * 256 + tid;
            int r = idx >> 4, cq = (idx & 15) * 4;
            f4 v = *(const f4*)&W[(size_t)(r0 + r) * C + c0 + cq];
            tile[r][cq] = v.x; tile[r][cq + 1] = v.y; tile[r][cq + 2] = v.z; tile[r][cq + 3] = v.w;
        }
        __syncthreads();
        #pragma unroll
        for (int p = 0; p < 4; ++p) {
            int idx = p * 256 + tid;
            int c = idx >> 4, rq = (idx & 15) * 4;
            half4 o;
            o.x = (_Float16)tile[rq][c];
            o.y = (_Float16)tile[rq + 1][c];
            o.z = (_Float16)tile[rq + 2][c];
            o.w = (_Float16)tile[rq + 3][c];
            *(half4*)&T[(size_t)(c0 + c) * 1024 + r0 + rq] = o;
        }
        return;
    }
    // ---- router: one wave per token ----
    int s = bid * 4 + (tid >> 6);
    int lane = tid & 63;
    int h = lane & 31, half = lane >> 5;
    const float* xr = x + (size_t)s * E + half * 512;
    const float* wr = Wr + (size_t)(half * 512) * H + h;
    float a0 = 0.f, a1 = 0.f, a2 = 0.f, a3 = 0.f;   // 4 chains: hide FMA latency
    #pragma unroll 4
    for (int e = 0; e < 512; e += 4) {
        a0 += xr[e]     * wr[e * H];
        a1 += xr[e + 1] * wr[(e + 1) * H];
        a2 += xr[e + 2] * wr[(e + 2) * H];
        a3 += xr[e + 3] * wr[(e + 3) * H];
    }
    float acc = (a0 + a1) + (a2 + a3);
    acc += __shfl_xor(acc, 32, 64);       // combine halves; all 64 lanes: logit[h]
    float logit = acc;
    float m = logit;
    #pragma unroll
    for (int off = 16; off; off >>= 1) m = fmaxf(m, __shfl_xor(m, off, 64));
    float ex = expf(logit - m);
    float Z = ex;
    #pragma unroll
    for (int off = 16; off; off >>= 1) Z += __shfl_xor(Z, off, 64);
    float p = ex / Z;
    float es = p * logf(p + 1e-8f);
    #pragma unroll
    for (int off = 16; off; off >>= 1) es += __shfl_xor(es, off, 64);
    float lse = m + logf(Z);
    // top-8: butterfly max with tie -> lowest index (jax.lax.top_k semantics)
    float lv = logit;
    float tv[KSEL]; int ti[KSEL];
    #pragma unroll
    for (int j = 0; j < KSEL; ++j) {
        float bv = lv; int bi = h;
        #pragma unroll
        for (int off = 16; off; off >>= 1) {
            float ov = __shfl_xor(bv, off, 64);
            int oi = __shfl_xor(bi, off, 64);
            if (ov > bv || (ov == bv && oi < bi)) { bv = ov; bi = oi; }
        }
        tv[j] = bv; ti[j] = bi;
        if (h == bi) lv = -INFINITY;
    }
    float Z2 = 0.f;
    #pragma unroll
    for (int j = 0; j < KSEL; ++j) Z2 += expf(tv[j] - tv[0]);
    if (lane < 32) pbuf[s * 32 + lane] = p;
    if (lane == 0) {
        entz[s * 2]     = es;
        entz[s * 2 + 1] = lse * lse;
        #pragma unroll
        for (int j = 0; j < KSEL; ++j) {
            head_idx[s * KSEL + j] = ti[j];
            head_w[s * KSEL + j]   = expf(tv[j] - tv[0]) / Z2;
        }
    }
    // fused x -> fp16 for this token's row (wave-cooperative, coalesced)
    const float* xrow = x + (size_t)s * E;
    _Float16* xhrow = xh + (size_t)s * E;
    #pragma unroll
    for (int t = 0; t < 4; ++t) {
        int e = t * 256 + lane * 4;
        f4 v = *(const f4*)&xrow[e];
        half4 o;
        o.x = (_Float16)v.x; o.y = (_Float16)v.y; o.z = (_Float16)v.z; o.w = (_Float16)v.w;
        *(half4*)&xhrow[e] = o;
    }
}

// ---------------- per-head ordered lists (ballot scan) + fused aux-loss block ----------------
__global__ __launch_bounds__(256) void order_kernel(
    const int* __restrict__ head_idx, const int* __restrict__ head_counts,
    int* __restrict__ order, int* __restrict__ hlen, float* __restrict__ out_counts,
    const float* __restrict__ pbuf, const float* __restrict__ entz,
    float* __restrict__ out_aux)
{
    int h = blockIdx.x, tid = threadIdx.x;
    if (h == H) {
        // ---- aux loss reduction (block 32) ----
        int hh = tid & 31, grp = tid >> 5;
        __shared__ float red[256], red2[256];
        __shared__ float psum[32];
        __shared__ int hist[32];
        if (tid < 32) hist[tid] = 0;
        float ps = 0.f;
        for (int s = grp; s < S; s += 8) ps += pbuf[s * 32 + hh];
        red[tid] = ps;
        float es = 0.f, zs = 0.f;
        for (int s = tid; s < S; s += 256) { es += entz[s * 2]; zs += entz[s * 2 + 1]; }
        red2[tid] = es;
        __syncthreads();
        if (grp == 0) {
            float v = 0.f;
            #pragma unroll
            for (int j = 0; j < 8; ++j) v += red[j * 32 + hh];
            psum[hh] = v;
        }
        __syncthreads();
        red[tid] = zs;
        for (int s = tid; s < S; s += 256)
            atomicAdd(&hist[head_idx[s * KSEL]], 1);
        __syncthreads();
        for (int stp = 128; stp; stp >>= 1) {
            if (tid < stp) { red[tid] += red[tid + stp]; red2[tid] += red2[tid + stp]; }
            __syncthreads();
        }
        if (tid == 0) {
            float bal = 0.f;
            for (int j = 0; j < H; ++j)
                bal += ((float)hist[j] / (float)S) * (psum[j] / (float)S);
            bal *= (float)H;
            float ent_loss = red2[0] / (float)S;
            float z = red[0] / (float)S * 0.01f;
            out_aux[0] = 0.01f * bal + 0.01f * ent_loss + z;
        }
        return;
    }
    int wave = tid >> 6, lane = tid & 63;
    __shared__ int wtot[4];
    int base = 0;
    int hc = head_counts[h];
    int v = head_idx[tid];
    for (int c0 = 0; c0 < SK; c0 += 256) {
        int vn = (c0 + 256 < SK) ? head_idx[c0 + 256 + tid] : 0;  // prefetch next chunk
        bool pred = (v == h);
        unsigned long long mask = __ballot(pred);
        int within = __popcll(mask & ((1ull << lane) - 1ull));
        if (lane == 0) wtot[wave] = __popcll(mask);
        __syncthreads();
        int pre = 0, tot = 0;
        #pragma unroll
        for (int w = 0; w < 4; ++w) { int t = wtot[w]; if (w < wave) pre += t; tot += t; }
        if (pred) order[h * MAXL + base + pre + within] = c0 + tid;
        base += tot;
        __syncthreads();
        v = vn;
    }
    if (tid == 0) {
        hlen[h] = base;
        out_counts[h] = (float)(hc + base);
    }
}

// ---------------- gathered QKV projection: B-only LDS dbuf, A direct-to-reg + fused RoPE ----------------
__global__ __launch_bounds__(256) void qkv_mfma(
    const _Float16* __restrict__ xh, const _Float16* __restrict__ Wt,
    const int* __restrict__ order, const int* __restrict__ hlen,
    const int* __restrict__ head_counts,
    _Float16* __restrict__ qh, _Float16* __restrict__ kh, _Float16* __restrict__ vT)
{
    int xid = blockIdx.x;
    int qkv = xid >> 5, h = xid & 31;
    int rt = blockIdx.y;
    int len = hlen[h];
    int row0 = rt * 64;
    if (row0 >= len) return;
    int hb = 0;
    for (int i = 0; i < h; ++i) hb += (hlen[i] + 31) & ~31;   // inline hstart prefix
    int lenp = (len + 31) & ~31;
    int tid = threadIdx.x, wave = tid >> 6, lane = tid & 63;
    int wm = wave >> 1, wn = wave & 1;
    int l32 = lane & 31, g = lane >> 5;

    __shared__ _Float16 Bs[2][128 * 64];

    // A operand: xh rows are k-contiguous == 32x32x16 A-frag layout -> registers, no LDS
    int arow_g = row0 + wm * 32 + l32;
    int tok = (arow_g < len) ? (order[h * MAXL + arow_g] >> 3) : 0;
    const _Float16* aptr = xh + (size_t)tok * E;

    const _Float16* Wb = Wt + (size_t)((qkv * H + h) * D) * E;

    auto stageB = [&](int buf, int k0) {
        #pragma unroll
        for (int it = 0; it < 4; ++it) {
            int f = it * 256 + tid;
            int row = f >> 3, c = f & 7;
            int sc = c ^ (row & 7);
            const _Float16* src = Wb + (size_t)row * E + k0 + sc * 8;
            GLOAD_LDS16(src, &Bs[buf][f * 8]);
        }
    };

    floatx16 acc[2] = {};
    half8 a_cur[4], a_nxt[4];
    #pragma unroll
    for (int ks = 0; ks < 4; ++ks)
        a_cur[ks] = *(const half8*)(aptr + ks * 16 + g * 8);

    auto compute = [&](int buf, half8* a) {
        #pragma unroll
        for (int ks = 0; ks < 4; ++ks) {
            int wchunk = ks * 2 + g;
            #pragma unroll
            for (int nf = 0; nf < 2; ++nf) {
                int brow = wn * 64 + nf * 32 + l32;
                half8 bf = *(const half8*)&Bs[buf][brow * 64 + (wchunk ^ (brow & 7)) * 8];
                acc[nf] = __builtin_amdgcn_mfma_f32_32x32x16_f16(a[ks], bf, acc[nf], 0, 0, 0);
            }
        }
    };

    stageB(0, 0);
    __syncthreads();
    int buf = 0;
    for (int k0 = 64; k0 < E; k0 += 64) {
        stageB(buf ^ 1, k0);
        #pragma unroll
        for (int ks = 0; ks < 4; ++ks)
            a_nxt[ks] = *(const half8*)(aptr + k0 + ks * 16 + g * 8);
        compute(buf, a_cur);
        __syncthreads();
        buf ^= 1;
        #pragma unroll
        for (int ks = 0; ks < 4; ++ks) a_cur[ks] = a_nxt[ks];
    }
    compute(buf, a_cur);

    if (qkv < 2) {
        // fused RoPE: round-trip acc through LDS (reuse Bs as 64x128 fp32 scratch)
        _Float16* dst = (qkv == 0) ? qh : kh;
        float* scr = (float*)&Bs[0][0];
        __syncthreads();   // all waves done reading Bs
        #pragma unroll
        for (int nf = 0; nf < 2; ++nf) {
            int col = wn * 64 + nf * 32 + l32;
            #pragma unroll
            for (int reg = 0; reg < 16; ++reg) {
                int rl = wm * 32 + (reg & 3) + 8 * (reg >> 2) + 4 * g;
                scr[rl * 128 + col] = acc[nf][reg];
            }
        }
        __syncthreads();
        int hc = head_counts[h];
        #pragma unroll
        for (int pass = 0; pass < 16; ++pass) {
            int idx = pass * 256 + tid;
            int r = idx >> 6, d2 = idx & 63;
            int slot = row0 + r;
            if (slot < len) {
                float v1 = scr[r * 128 + d2], v2 = scr[r * 128 + 64 + d2];
                int p = slot + hc;
                p = p < 0 ? 0 : (p > 8191 ? 8191 : p);
                float inv = exp2f((float)d2 * -0.20762050f);  // 10000^(-d2/64)
                float ang = (float)p * inv;
                float cs = cosf(ang), sn = sinf(ang);
                _Float16* dp = dst + ((size_t)hb + slot) * D;
                dp[d2]      = (_Float16)(v1 * cs - v2 * sn);
                dp[d2 + 64] = (_Float16)(v2 * cs + v1 * sn);
            }
        }
    } else {
        #pragma unroll
        for (int nf = 0; nf < 2; ++nf) {
            int col = wn * 64 + nf * 32 + l32;
            #pragma unroll
            for (int q4 = 0; q4 < 4; ++q4) {
                int slot0 = row0 + wm * 32 + 8 * q4 + 4 * g;
                _Float16* vp = vT + (size_t)hb * D + (size_t)col * lenp + slot0;
                if (slot0 + 3 < len) {
                    half4 o;
                    o.x = (_Float16)acc[nf][q4 * 4 + 0];
                    o.y = (_Float16)acc[nf][q4 * 4 + 1];
                    o.z = (_Float16)acc[nf][q4 * 4 + 2];
                    o.w = (_Float16)acc[nf][q4 * 4 + 3];
                    *(half4*)vp = o;
                } else {
                    #pragma unroll
                    for (int r2 = 0; r2 < 4; ++r2)
                        if (slot0 + r2 < len) vp[r2] = (_Float16)acc[nf][q4 * 4 + r2];
                }
            }
        }
    }
}

// ---------------- per-head causal flash attention: 2-wave split-K, MFMA 32x32x16 ----------------
__global__ __launch_bounds__(128) void attn_mfma(
    const _Float16* __restrict__ qh, const _Float16* __restrict__ kh,
    const _Float16* __restrict__ vT,
    const int* __restrict__ order, const int* __restrict__ hlen,
    const float* __restrict__ head_w, _Float16* __restrict__ ao)
{
    int h = blockIdx.x >> 5, qt = blockIdx.x & 31;
    int len = hlen[h];
    int row0 = qt * 32;
    if (row0 >= len) return;
    int hb = 0;
    for (int i = 0; i < h; ++i) hb += (hlen[i] + 31) & ~31;
    int lenp = (len + 31) & ~31;
    int tid = threadIdx.x;
    int w = tid >> 6, lane = tid & 63;
    int l32 = lane & 31, g = lane >> 5;
    int srow = lane >> 1, shalf = lane & 1;

    __shared__ float Sld[2][32 * SSTR];
    __shared__ _Float16 Pld[2][32 * PSTR];
    __shared__ float alphaLd[2][32];
    __shared__ float mlLd[32][4];     // m0,l0,m1,l1
    __shared__ float facLd[32][3];    // f1, hw/l*, f0
    __shared__ int flatLd[32];
    __shared__ float Obuf[32][128];

    if (tid < 32) {
        int r = row0 + tid;
        flatLd[tid] = (r < len) ? order[h * MAXL + r] : -1;
    }

    const _Float16* qrow = qh + ((size_t)hb + row0 + l32) * D;
    half8 qf[8];
    #pragma unroll
    for (int t = 0; t < 8; ++t) qf[t] = *(const half8*)(qrow + t * 16 + g * 8);

    floatx16 O[4] = {};
    float m_run = -INFINITY, l_run = 0.f;

    if (w <= qt) {
        half8 kf[8], kfn[8], vv[8];
        {
            const _Float16* krow = kh + ((size_t)hb + w * 32 + l32) * D;
            #pragma unroll
            for (int t = 0; t < 8; ++t) kf[t] = *(const half8*)(krow + t * 16 + g * 8);
        }
        for (int kt = w; kt <= qt; kt += 2) {
            int col0 = kt * 32;
            floatx16 Sc = {};
            #pragma unroll
            for (int t = 0; t < 8; ++t)
                Sc = __builtin_amdgcn_mfma_f32_32x32x16_f16(qf[t], kf[t], Sc, 0, 0, 0);
            // prefetch this tile's V and next K (overlap with softmax)
            #pragma unroll
            for (int nt = 0; nt < 4; ++nt) {
                const _Float16* vp = vT + (size_t)hb * D + (size_t)(nt * 32 + l32) * lenp + col0;
                vv[nt * 2]     = *(const half8*)(vp + g * 8);
                vv[nt * 2 + 1] = *(const half8*)(vp + 16 + g * 8);
            }
            if (kt + 2 <= qt) {
                const _Float16* krow = kh + ((size_t)hb + col0 + 64 + l32) * D;
                #pragma unroll
                for (int t = 0; t < 8; ++t) kfn[t] = *(const half8*)(krow + t * 16 + g * 8);
            }
            bool diag = (kt == qt);
            #pragma unroll
            for (int reg = 0; reg < 16; ++reg) {
                int row = (reg & 3) + 8 * (reg >> 2) + 4 * g;
                float s = Sc[reg] * ATTN_SCALE;
                if (diag && l32 > row) s = -1e30f;
                Sld[w][row * SSTR + l32] = s;
            }
            __builtin_amdgcn_wave_barrier();
            const float* sp = &Sld[w][srow * SSTR + shalf * 16];
            float va[16];
            *(f4*)(va)      = *(const f4*)(sp);
            *(f4*)(va + 4)  = *(const f4*)(sp + 4);
            *(f4*)(va + 8)  = *(const f4*)(sp + 8);
            *(f4*)(va + 12) = *(const f4*)(sp + 12);
            float mt_ = va[0];
            #pragma unroll
            for (int j = 1; j < 16; ++j) mt_ = fmaxf(mt_, va[j]);
            mt_ = fmaxf(mt_, __shfl_xor(mt_, 1, 64));
            float m_new = fmaxf(m_run, mt_);
            float alpha = __expf(m_run - m_new);
            float p[16], tsum = 0.f;
            #pragma unroll
            for (int j = 0; j < 16; ++j) { p[j] = __expf(va[j] - m_new); tsum += p[j]; }
            tsum += __shfl_xor(tsum, 1, 64);
            l_run = l_run * alpha + tsum;
            m_run = m_new;
            half8 ph0, ph1;
            #pragma unroll
            for (int j = 0; j < 8; ++j) { ph0[j] = (_Float16)p[j]; ph1[j] = (_Float16)p[j + 8]; }
            *(half8*)&Pld[w][srow * PSTR + shalf * 16]     = ph0;
            *(half8*)&Pld[w][srow * PSTR + shalf * 16 + 8] = ph1;
            if (shalf == 0) alphaLd[w][srow] = alpha;
            __builtin_amdgcn_wave_barrier();
            f4 al[4];
            #pragma unroll
            for (int qq = 0; qq < 4; ++qq) al[qq] = *(const f4*)&alphaLd[w][4 * g + 8 * qq];
            #pragma unroll
            for (int reg = 0; reg < 16; ++reg) {
                float av = al[reg >> 2][reg & 3];
                O[0][reg] *= av; O[1][reg] *= av; O[2][reg] *= av; O[3][reg] *= av;
            }
            half8 pf0 = *(const half8*)&Pld[w][l32 * PSTR + g * 8];
            half8 pf1 = *(const half8*)&Pld[w][l32 * PSTR + 16 + g * 8];
            #pragma unroll
            for (int nt = 0; nt < 4; ++nt) {
                O[nt] = __builtin_amdgcn_mfma_f32_32x32x16_f16(pf0, vv[nt * 2],     O[nt], 0, 0, 0);
                O[nt] = __builtin_amdgcn_mfma_f32_32x32x16_f16(pf1, vv[nt * 2 + 1], O[nt], 0, 0, 0);
            }
            __builtin_amdgcn_wave_barrier();
            #pragma unroll
            for (int t = 0; t < 8; ++t) kf[t] = kfn[t];
        }
    }
    // ---- merge the two waves' partial (m, l, O) ----
    if (shalf == 0) { mlLd[srow][w * 2] = m_run; mlLd[srow][w * 2 + 1] = l_run; }
    __syncthreads();
    if (tid < 32) {
        float m0 = mlLd[tid][0], l0 = mlLd[tid][1];
        float m1 = mlLd[tid][2], l1 = mlLd[tid][3];
        float ms = fmaxf(m0, m1);
        float f0 = __expf(m0 - ms), f1 = __expf(m1 - ms);
        float lt = f0 * l0 + f1 * l1;
        int flat = flatLd[tid];
        float hw = (flat >= 0) ? head_w[flat] : 0.f;
        facLd[tid][0] = f1;
        facLd[tid][1] = hw / lt;
        facLd[tid][2] = f0;
    }
    __syncthreads();
    if (w == 1) {
        #pragma unroll
        for (int nt = 0; nt < 4; ++nt) {
            int col = nt * 32 + l32;
            #pragma unroll
            for (int reg = 0; reg < 16; ++reg) {
                int row = (reg & 3) + 8 * (reg >> 2) + 4 * g;
                Obuf[row][col] = O[nt][reg] * facLd[row][0];
            }
        }
    }
    __syncthreads();
    if (w == 0) {
        #pragma unroll
        for (int nt = 0; nt < 4; ++nt) {
            int col = nt * 32 + l32;
            #pragma unroll
            for (int reg = 0; reg < 16; ++reg) {
                int row = (reg & 3) + 8 * (reg >> 2) + 4 * g;
                int flat = flatLd[row];
                if (flat >= 0) {
                    float val = (O[nt][reg] * facLd[row][2] + Obuf[row][col]) * facLd[row][1];
                    ao[(size_t)flat * D + col] = (_Float16)val;
                }
            }
        }
    }
}

// ---------------- output projection: B-only LDS dbuf MFMA GEMM, A direct-to-reg ----------------
__global__ __launch_bounds__(256) void out_mfma(
    const _Float16* __restrict__ A, const _Float16* __restrict__ Bt,
    float* __restrict__ C)
{
    int n0 = blockIdx.x * 64, m0 = blockIdx.y * 64;
    int tid = threadIdx.x, wave = tid >> 6, lane = tid & 63;
    int wm = wave >> 1, wn = wave & 1;
    int l32 = lane & 31, g = lane >> 5;

    __shared__ _Float16 Bs[2][64 * 64];

    const _Float16* aptr = A + (size_t)(m0 + wm * 32 + l32) * 1024;

    auto stageB = [&](int buf, int k0) {
        #pragma unroll
        for (int it = 0; it < 2; ++it) {
            int f = it * 256 + tid;
            int row = f >> 3, c = f & 7;
            int sc = c ^ (row & 7);
            GLOAD_LDS16(Bt + (size_t)(n0 + row) * 1024 + k0 + sc * 8, &Bs[buf][f * 8]);
        }
    };

    floatx16 acc = {};
    int brow = wn * 32 + l32;
    half8 a_cur[4], a_nxt[4];
    #pragma unroll
    for (int ks = 0; ks < 4; ++ks)
        a_cur[ks] = *(const half8*)(aptr + ks * 16 + g * 8);

    auto compute = [&](int buf, half8* a) {
        #pragma unroll
        for (int ks = 0; ks < 4; ++ks) {
            int wchunk = ks * 2 + g;
            half8 bf = *(const half8*)&Bs[buf][brow * 64 + (wchunk ^ (brow & 7)) * 8];
            acc = __builtin_amdgcn_mfma_f32_32x32x16_f16(a[ks], bf, acc, 0, 0, 0);
        }
    };

    stageB(0, 0);
    __syncthreads();
    int buf = 0;
    for (int k0 = 64; k0 < 1024; k0 += 64) {
        stageB(buf ^ 1, k0);
        #pragma unroll
        for (int ks = 0; ks < 4; ++ks)
            a_nxt[ks] = *(const half8*)(aptr + k0 + ks * 16 + g * 8);
        compute(buf, a_cur);
        __syncthreads();
        buf ^= 1;
        #pragma unroll
        for (int ks = 0; ks < 4; ++ks) a_cur[ks] = a_nxt[ks];
    }
    compute(buf, a_cur);

    int col = n0 + wn * 32 + l32;
    #pragma unroll
    for (int reg = 0; reg < 16; ++reg) {
        int row = m0 + wm * 32 + (reg & 3) + 8 * (reg >> 2) + 4 * g;
        C[(size_t)row * 1024 + col] = acc[reg];
    }
}

extern "C" void kernel_launch(void* const* d_in, const int* in_sizes, int n_in,
                              void* d_out, int out_size, void* d_ws, size_t ws_size,
                              hipStream_t stream)
{
    const float* x  = (const float*)d_in[0];
    const float* Wq = (const float*)d_in[1];
    const float* Wk = (const float*)d_in[2];
    const float* Wv = (const float*)d_in[3];
    const float* Wr = (const float*)d_in[4];
    const float* Wo = (const float*)d_in[5];
    const int* head_counts = (const int*)d_in[6];
    float* out = (float*)d_out;

    float* head_w = (float*)d_ws;                 // SK
    float* pbuf   = head_w + SK;                  // S*32
    float* entz   = pbuf + S * 32;                // S*2
    int* head_idx = (int*)(entz + S * 2);         // SK
    int* order    = head_idx + SK;                // H*MAXL
    int* hlen     = order + H * MAXL;             // 32 (pad 64)
    _Float16* xh   = (_Float16*)(hlen + 64);      // S*E
    _Float16* aoh  = xh + (size_t)S * E;          // SK*D
    _Float16* Wqkt = aoh + (size_t)SK * D;        // 3*HD*E
    _Float16* Wot  = Wqkt + (size_t)3 * HD * E;   // 1024*1024
    _Float16* qh   = Wot + (size_t)1024 * 1024;   // CAP*D
    _Float16* kh   = qh + (size_t)CAP * D;        // CAP*D
    _Float16* vT   = kh + (size_t)CAP * D;        // CAP*D

    prep_kernel<<<256 + 4096, 256, 0, stream>>>(x, Wr, Wq, Wk, Wv, Wo, Wqkt, Wot,
                                                head_idx, head_w, pbuf, entz, xh);
    order_kernel<<<H + 1, 256, 0, stream>>>(head_idx, head_counts, order, hlen,
                                            out + (size_t)S * E, pbuf, entz,
                                            out + (size_t)S * E + H);
    qkv_mfma<<<dim3(96, 16), 256, 0, stream>>>(xh, Wqkt, order, hlen, head_counts,
                                               qh, kh, vT);
    attn_mfma<<<H * 32, 128, 0, stream>>>(qh, kh, vT, order, hlen, head_w, aoh);
    out_mfma<<<dim3(16, 16), 256, 0, stream>>>(aoh, Wot, out);
}

// Round 10
// 218.832 us; speedup vs baseline: 1.1052x; 1.0211x over previous
//
#include <hip/hip_runtime.h>
#include <math.h>

#define S 1024
#define E 1024
#define H 32
#define KSEL 8
#define D 128
#define HD 4096      // H*D
#define SK 8192      // S*KSEL
#define MAXL 1024
#define CAP 9216     // SK + H*31 padding (per-head padded to 32)
#define ATTN_SCALE 0.08838834764831845f  // 1/sqrt(128)
#define SSTR 36
#define PSTR 40

typedef _Float16 half8 __attribute__((ext_vector_type(8)));
typedef _Float16 half4 __attribute__((ext_vector_type(4)));
typedef float floatx4 __attribute__((ext_vector_type(4)));
typedef float floatx16 __attribute__((ext_vector_type(16)));
typedef float f4 __attribute__((ext_vector_type(4)));

// async 16B global -> LDS (lands at wave-uniform base + lane*16)
#define GLOAD_LDS16(gsrc, ldst) \
    __builtin_amdgcn_global_load_lds( \
        (const __attribute__((address_space(1))) void*)(gsrc), \
        (__attribute__((address_space(3))) void*)(ldst), 16, 0, 0)

// ---------------- router: one wave per token + x->fp16 conversion fused ----------------
__global__ __launch_bounds__(256) void router_kernel(
    const float* __restrict__ x, const float* __restrict__ Wr,
    int* __restrict__ head_idx, float* __restrict__ head_w,
    float* __restrict__ pbuf, float* __restrict__ entz,
    _Float16* __restrict__ xh)
{
    int tid = threadIdx.x;
    int s = blockIdx.x * 4 + (tid >> 6);
    int lane = tid & 63;
    int h = lane & 31, half = lane >> 5;
    const float* xr = x + (size_t)s * E + half * 512;
    const float* wr = Wr + (size_t)(half * 512) * H + h;
    float a0 = 0.f, a1 = 0.f, a2 = 0.f, a3 = 0.f;   // 4 chains: hide FMA latency
    #pragma unroll 4
    for (int e = 0; e < 512; e += 4) {
        a0 += xr[e]     * wr[e * H];
        a1 += xr[e + 1] * wr[(e + 1) * H];
        a2 += xr[e + 2] * wr[(e + 2) * H];
        a3 += xr[e + 3] * wr[(e + 3) * H];
    }
    float acc = (a0 + a1) + (a2 + a3);
    acc += __shfl_xor(acc, 32, 64);       // combine halves; all 64 lanes: logit[h]
    float logit = acc;
    float m = logit;
    #pragma unroll
    for (int off = 16; off; off >>= 1) m = fmaxf(m, __shfl_xor(m, off, 64));
    float ex = expf(logit - m);
    float Z = ex;
    #pragma unroll
    for (int off = 16; off; off >>= 1) Z += __shfl_xor(Z, off, 64);
    float p = ex / Z;
    float es = p * logf(p + 1e-8f);
    #pragma unroll
    for (int off = 16; off; off >>= 1) es += __shfl_xor(es, off, 64);
    float lse = m + logf(Z);
    // top-8: butterfly max with tie -> lowest index (jax.lax.top_k semantics)
    float lv = logit;
    float tv[KSEL]; int ti[KSEL];
    #pragma unroll
    for (int j = 0; j < KSEL; ++j) {
        float bv = lv; int bi = h;
        #pragma unroll
        for (int off = 16; off; off >>= 1) {
            float ov = __shfl_xor(bv, off, 64);
            int oi = __shfl_xor(bi, off, 64);
            if (ov > bv || (ov == bv && oi < bi)) { bv = ov; bi = oi; }
        }
        tv[j] = bv; ti[j] = bi;
        if (h == bi) lv = -INFINITY;
    }
    float Z2 = 0.f;
    #pragma unroll
    for (int j = 0; j < KSEL; ++j) Z2 += expf(tv[j] - tv[0]);
    if (lane < 32) pbuf[s * 32 + lane] = p;
    if (lane == 0) {
        entz[s * 2]     = es;
        entz[s * 2 + 1] = lse * lse;
        #pragma unroll
        for (int j = 0; j < KSEL; ++j) {
            head_idx[s * KSEL + j] = ti[j];
            head_w[s * KSEL + j]   = expf(tv[j] - tv[0]) / Z2;
        }
    }
    // fused x -> fp16 for this token's row (wave-cooperative, coalesced)
    const float* xrow = x + (size_t)s * E;
    _Float16* xhrow = xh + (size_t)s * E;
    #pragma unroll
    for (int t = 0; t < 4; ++t) {
        int e = t * 256 + lane * 4;
        f4 v = *(const f4*)&xrow[e];
        half4 o;
        o.x = (_Float16)v.x; o.y = (_Float16)v.y; o.z = (_Float16)v.z; o.w = (_Float16)v.w;
        *(half4*)&xhrow[e] = o;
    }
}

// ---------------- merged: order scan (blocks 0..31) + aux (32) + convW (33..) ----------------
// Order/aux blocks dispatch first (latency-bound, mostly-idle machine); the HBM-bound
// convW stream fills the GPU behind them -> stage cost = max, not sum.
__global__ __launch_bounds__(256) void order_conv_kernel(
    const int* __restrict__ head_idx, const int* __restrict__ head_counts,
    int* __restrict__ order, int* __restrict__ hlen, float* __restrict__ out_counts,
    const float* __restrict__ pbuf, const float* __restrict__ entz,
    float* __restrict__ out_aux,
    const float* __restrict__ Wq, const float* __restrict__ Wk,
    const float* __restrict__ Wv, const float* __restrict__ Wo,
    _Float16* __restrict__ Wqkt, _Float16* __restrict__ Wot)
{
    int bid = blockIdx.x, tid = threadIdx.x;
    if (bid >= 33) {
        // ---- weight transpose+convert ----
        int cb = bid - 33;
        int z = cb >> 10, rem = cb & 1023;
        if (z == 3 && (rem >> 4) >= 16) return;
        const float* W = (z == 0) ? Wq : (z == 1) ? Wk : (z == 2) ? Wv : Wo;
        _Float16* T = (z < 3) ? (Wqkt + (size_t)z * HD * E) : Wot;
        int C = (z < 3) ? HD : 1024;
        int r0 = (rem & 15) * 64, c0 = (rem >> 4) * 64;
        __shared__ float tile[64][65];
        #pragma unroll
        for (int p = 0; p < 4; ++p) {
            int idx = p * 256 + tid;
            int r = idx >> 4, cq = (idx & 15) * 4;
            f4 v = *(const f4*)&W[(size_t)(r0 + r) * C + c0 + cq];
            tile[r][cq] = v.x; tile[r][cq + 1] = v.y; tile[r][cq + 2] = v.z; tile[r][cq + 3] = v.w;
        }
        __syncthreads();
        #pragma unroll
        for (int p = 0; p < 2; ++p) {
            int idx = p * 256 + tid;
            int c = idx >> 3, r8 = (idx & 7) * 8;
            half8 o;
            #pragma unroll
            for (int j = 0; j < 8; ++j) o[j] = (_Float16)tile[r8 + j][c];
            *(half8*)&T[(size_t)(c0 + c) * 1024 + r0 + r8] = o;
        }
        return;
    }
    if (bid == H) {
        // ---- aux loss reduction ----
        int hh = tid & 31, grp = tid >> 5;
        __shared__ float red[256], red2[256];
        __shared__ float psum[32];
        __shared__ int hist[32];
        if (tid < 32) hist[tid] = 0;
        float ps = 0.f;
        for (int s = grp; s < S; s += 8) ps += pbuf[s * 32 + hh];
        red[tid] = ps;
        float es = 0.f, zs = 0.f;
        for (int s = tid; s < S; s += 256) { es += entz[s * 2]; zs += entz[s * 2 + 1]; }
        red2[tid] = es;
        __syncthreads();
        if (grp == 0) {
            float v = 0.f;
            #pragma unroll
            for (int j = 0; j < 8; ++j) v += red[j * 32 + hh];
            psum[hh] = v;
        }
        __syncthreads();
        red[tid] = zs;
        for (int s = tid; s < S; s += 256)
            atomicAdd(&hist[head_idx[s * KSEL]], 1);
        __syncthreads();
        for (int stp = 128; stp; stp >>= 1) {
            if (tid < stp) { red[tid] += red[tid + stp]; red2[tid] += red2[tid + stp]; }
            __syncthreads();
        }
        if (tid == 0) {
            float bal = 0.f;
            for (int j = 0; j < H; ++j)
                bal += ((float)hist[j] / (float)S) * (psum[j] / (float)S);
            bal *= (float)H;
            float ent_loss = red2[0] / (float)S;
            float z = red[0] / (float)S * 0.01f;
            out_aux[0] = 0.01f * bal + 0.01f * ent_loss + z;
        }
        return;
    }
    // ---- per-head ordered list (ballot scan, software-pipelined) ----
    int h = bid;
    int wave = tid >> 6, lane = tid & 63;
    __shared__ int wtot[4];
    int base = 0;
    int hc = head_counts[h];
    int v = head_idx[tid];
    for (int c0 = 0; c0 < SK; c0 += 256) {
        int vn = (c0 + 256 < SK) ? head_idx[c0 + 256 + tid] : 0;  // prefetch next chunk
        bool pred = (v == h);
        unsigned long long mask = __ballot(pred);
        int within = __popcll(mask & ((1ull << lane) - 1ull));
        if (lane == 0) wtot[wave] = __popcll(mask);
        __syncthreads();
        int pre = 0, tot = 0;
        #pragma unroll
        for (int w = 0; w < 4; ++w) { int t = wtot[w]; if (w < wave) pre += t; tot += t; }
        if (pred) order[h * MAXL + base + pre + within] = c0 + tid;
        base += tot;
        __syncthreads();
        v = vn;
    }
    if (tid == 0) {
        hlen[h] = base;
        out_counts[h] = (float)(hc + base);
    }
}

// ---------------- gathered QKV projection: B-only LDS dbuf, A direct-to-reg + fused RoPE ----------------
__global__ __launch_bounds__(256) void qkv_mfma(
    const _Float16* __restrict__ xh, const _Float16* __restrict__ Wt,
    const int* __restrict__ order, const int* __restrict__ hlen,
    const int* __restrict__ head_counts,
    _Float16* __restrict__ qh, _Float16* __restrict__ kh, _Float16* __restrict__ vT)
{
    int xid = blockIdx.x;
    int qkv = xid >> 5, h = xid & 31;
    int rt = blockIdx.y;
    int len = hlen[h];
    int row0 = rt * 64;
    if (row0 >= len) return;
    int hb = 0;
    for (int i = 0; i < h; ++i) hb += (hlen[i] + 31) & ~31;   // inline hstart prefix
    int lenp = (len + 31) & ~31;
    int tid = threadIdx.x, wave = tid >> 6, lane = tid & 63;
    int wm = wave >> 1, wn = wave & 1;
    int l32 = lane & 31, g = lane >> 5;

    __shared__ _Float16 Bs[2][128 * 64];

    // A operand: xh rows are k-contiguous == 32x32x16 A-frag layout -> registers, no LDS
    int arow_g = row0 + wm * 32 + l32;
    int tok = (arow_g < len) ? (order[h * MAXL + arow_g] >> 3) : 0;
    const _Float16* aptr = xh + (size_t)tok * E;

    const _Float16* Wb = Wt + (size_t)((qkv * H + h) * D) * E;

    auto stageB = [&](int buf, int k0) {
        #pragma unroll
        for (int it = 0; it < 4; ++it) {
            int f = it * 256 + tid;
            int row = f >> 3, c = f & 7;
            int sc = c ^ (row & 7);
            const _Float16* src = Wb + (size_t)row * E + k0 + sc * 8;
            GLOAD_LDS16(src, &Bs[buf][f * 8]);
        }
    };

    floatx16 acc[2] = {};
    half8 a_cur[4], a_nxt[4];
    #pragma unroll
    for (int ks = 0; ks < 4; ++ks)
        a_cur[ks] = *(const half8*)(aptr + ks * 16 + g * 8);

    auto compute = [&](int buf, half8* a) {
        #pragma unroll
        for (int ks = 0; ks < 4; ++ks) {
            int wchunk = ks * 2 + g;
            #pragma unroll
            for (int nf = 0; nf < 2; ++nf) {
                int brow = wn * 64 + nf * 32 + l32;
                half8 bf = *(const half8*)&Bs[buf][brow * 64 + (wchunk ^ (brow & 7)) * 8];
                acc[nf] = __builtin_amdgcn_mfma_f32_32x32x16_f16(a[ks], bf, acc[nf], 0, 0, 0);
            }
        }
    };

    stageB(0, 0);
    __syncthreads();
    int buf = 0;
    for (int k0 = 64; k0 < E; k0 += 64) {
        stageB(buf ^ 1, k0);
        #pragma unroll
        for (int ks = 0; ks < 4; ++ks)
            a_nxt[ks] = *(const half8*)(aptr + k0 + ks * 16 + g * 8);
        compute(buf, a_cur);
        __syncthreads();
        buf ^= 1;
        #pragma unroll
        for (int ks = 0; ks < 4; ++ks) a_cur[ks] = a_nxt[ks];
    }
    compute(buf, a_cur);

    if (qkv < 2) {
        // fused RoPE: round-trip acc through LDS (reuse Bs as 64x128 fp32 scratch)
        _Float16* dst = (qkv == 0) ? qh : kh;
        float* scr = (float*)&Bs[0][0];
        __syncthreads();   // all waves done reading Bs
        #pragma unroll
        for (int nf = 0; nf < 2; ++nf) {
            int col = wn * 64 + nf * 32 + l32;
            #pragma unroll
            for (int reg = 0; reg < 16; ++reg) {
                int rl = wm * 32 + (reg & 3) + 8 * (reg >> 2) + 4 * g;
                scr[rl * 128 + col] = acc[nf][reg];
            }
        }
        __syncthreads();
        int hc = head_counts[h];
        #pragma unroll
        for (int pass = 0; pass < 16; ++pass) {
            int idx = pass * 256 + tid;
            int r = idx >> 6, d2 = idx & 63;
            int slot = row0 + r;
            if (slot < len) {
                float v1 = scr[r * 128 + d2], v2 = scr[r * 128 + 64 + d2];
                int p = slot + hc;
                p = p < 0 ? 0 : (p > 8191 ? 8191 : p);
                float inv = exp2f((float)d2 * -0.20762050f);  // 10000^(-d2/64)
                float ang = (float)p * inv;
                float cs = cosf(ang), sn = sinf(ang);
                _Float16* dp = dst + ((size_t)hb + slot) * D;
                dp[d2]      = (_Float16)(v1 * cs - v2 * sn);
                dp[d2 + 64] = (_Float16)(v2 * cs + v1 * sn);
            }
        }
    } else {
        #pragma unroll
        for (int nf = 0; nf < 2; ++nf) {
            int col = wn * 64 + nf * 32 + l32;
            #pragma unroll
            for (int q4 = 0; q4 < 4; ++q4) {
                int slot0 = row0 + wm * 32 + 8 * q4 + 4 * g;
                _Float16* vp = vT + (size_t)hb * D + (size_t)col * lenp + slot0;
                if (slot0 + 3 < len) {
                    half4 o;
                    o.x = (_Float16)acc[nf][q4 * 4 + 0];
                    o.y = (_Float16)acc[nf][q4 * 4 + 1];
                    o.z = (_Float16)acc[nf][q4 * 4 + 2];
                    o.w = (_Float16)acc[nf][q4 * 4 + 3];
                    *(half4*)vp = o;
                } else {
                    #pragma unroll
                    for (int r2 = 0; r2 < 4; ++r2)
                        if (slot0 + r2 < len) vp[r2] = (_Float16)acc[nf][q4 * 4 + r2];
                }
            }
        }
    }
}

// ---------------- per-head causal flash attention: 2-wave split-K, MFMA 32x32x16 ----------------
__global__ __launch_bounds__(128) void attn_mfma(
    const _Float16* __restrict__ qh, const _Float16* __restrict__ kh,
    const _Float16* __restrict__ vT,
    const int* __restrict__ order, const int* __restrict__ hlen,
    const float* __restrict__ head_w, _Float16* __restrict__ ao)
{
    int h = blockIdx.x >> 5, qt = blockIdx.x & 31;
    int len = hlen[h];
    int row0 = qt * 32;
    if (row0 >= len) return;
    int hb = 0;
    for (int i = 0; i < h; ++i) hb += (hlen[i] + 31) & ~31;
    int lenp = (len + 31) & ~31;
    int tid = threadIdx.x;
    int w = tid >> 6, lane = tid & 63;
    int l32 = lane & 31, g = lane >> 5;
    int srow = lane >> 1, shalf = lane & 1;

    __shared__ float Sld[2][32 * SSTR];
    __shared__ _Float16 Pld[2][32 * PSTR];
    __shared__ float alphaLd[2][32];
    __shared__ float mlLd[32][4];     // m0,l0,m1,l1
    __shared__ float facLd[32][3];    // f1, hw/l*, f0
    __shared__ int flatLd[32];
    __shared__ float Obuf[32][128];

    if (tid < 32) {
        int r = row0 + tid;
        flatLd[tid] = (r < len) ? order[h * MAXL + r] : -1;
    }

    const _Float16* qrow = qh + ((size_t)hb + row0 + l32) * D;
    half8 qf[8];
    #pragma unroll
    for (int t = 0; t < 8; ++t) qf[t] = *(const half8*)(qrow + t * 16 + g * 8);

    floatx16 O[4] = {};
    float m_run = -INFINITY, l_run = 0.f;

    if (w <= qt) {
        half8 kf[8], kfn[8], vv[8];
        {
            const _Float16* krow = kh + ((size_t)hb + w * 32 + l32) * D;
            #pragma unroll
            for (int t = 0; t < 8; ++t) kf[t] = *(const half8*)(krow + t * 16 + g * 8);
        }
        for (int kt = w; kt <= qt; kt += 2) {
            int col0 = kt * 32;
            floatx16 Sc = {};
            #pragma unroll
            for (int t = 0; t < 8; ++t)
                Sc = __builtin_amdgcn_mfma_f32_32x32x16_f16(qf[t], kf[t], Sc, 0, 0, 0);
            // prefetch this tile's V and next K (overlap with softmax)
            #pragma unroll
            for (int nt = 0; nt < 4; ++nt) {
                const _Float16* vp = vT + (size_t)hb * D + (size_t)(nt * 32 + l32) * lenp + col0;
                vv[nt * 2]     = *(const half8*)(vp + g * 8);
                vv[nt * 2 + 1] = *(const half8*)(vp + 16 + g * 8);
            }
            if (kt + 2 <= qt) {
                const _Float16* krow = kh + ((size_t)hb + col0 + 64 + l32) * D;
                #pragma unroll
                for (int t = 0; t < 8; ++t) kfn[t] = *(const half8*)(krow + t * 16 + g * 8);
            }
            bool diag = (kt == qt);
            #pragma unroll
            for (int reg = 0; reg < 16; ++reg) {
                int row = (reg & 3) + 8 * (reg >> 2) + 4 * g;
                float s = Sc[reg] * ATTN_SCALE;
                if (diag && l32 > row) s = -1e30f;
                Sld[w][row * SSTR + l32] = s;
            }
            __builtin_amdgcn_wave_barrier();
            const float* sp = &Sld[w][srow * SSTR + shalf * 16];
            float va[16];
            *(f4*)(va)      = *(const f4*)(sp);
            *(f4*)(va + 4)  = *(const f4*)(sp + 4);
            *(f4*)(va + 8)  = *(const f4*)(sp + 8);
            *(f4*)(va + 12) = *(const f4*)(sp + 12);
            float mt_ = va[0];
            #pragma unroll
            for (int j = 1; j < 16; ++j) mt_ = fmaxf(mt_, va[j]);
            mt_ = fmaxf(mt_, __shfl_xor(mt_, 1, 64));
            float m_new = fmaxf(m_run, mt_);
            float alpha = __expf(m_run - m_new);
            float p[16], tsum = 0.f;
            #pragma unroll
            for (int j = 0; j < 16; ++j) { p[j] = __expf(va[j] - m_new); tsum += p[j]; }
            tsum += __shfl_xor(tsum, 1, 64);
            l_run = l_run * alpha + tsum;
            m_run = m_new;
            half8 ph0, ph1;
            #pragma unroll
            for (int j = 0; j < 8; ++j) { ph0[j] = (_Float16)p[j]; ph1[j] = (_Float16)p[j + 8]; }
            *(half8*)&Pld[w][srow * PSTR + shalf * 16]     = ph0;
            *(half8*)&Pld[w][srow * PSTR + shalf * 16 + 8] = ph1;
            if (shalf == 0) alphaLd[w][srow] = alpha;
            __builtin_amdgcn_wave_barrier();
            f4 al[4];
            #pragma unroll
            for (int qq = 0; qq < 4; ++qq) al[qq] = *(const f4*)&alphaLd[w][4 * g + 8 * qq];
            #pragma unroll
            for (int reg = 0; reg < 16; ++reg) {
                float av = al[reg >> 2][reg & 3];
                O[0][reg] *= av; O[1][reg] *= av; O[2][reg] *= av; O[3][reg] *= av;
            }
            half8 pf0 = *(const half8*)&Pld[w][l32 * PSTR + g * 8];
            half8 pf1 = *(const half8*)&Pld[w][l32 * PSTR + 16 + g * 8];
            #pragma unroll
            for (int nt = 0; nt < 4; ++nt) {
                O[nt] = __builtin_amdgcn_mfma_f32_32x32x16_f16(pf0, vv[nt * 2],     O[nt], 0, 0, 0);
                O[nt] = __builtin_amdgcn_mfma_f32_32x32x16_f16(pf1, vv[nt * 2 + 1], O[nt], 0, 0, 0);
            }
            __builtin_amdgcn_wave_barrier();
            #pragma unroll
            for (int t = 0; t < 8; ++t) kf[t] = kfn[t];
        }
    }
    // ---- merge the two waves' partial (m, l, O) ----
    if (shalf == 0) { mlLd[srow][w * 2] = m_run; mlLd[srow][w * 2 + 1] = l_run; }
    __syncthreads();
    if (tid < 32) {
        float m0 = mlLd[tid][0], l0 = mlLd[tid][1];
        float m1 = mlLd[tid][2], l1 = mlLd[tid][3];
        float ms = fmaxf(m0, m1);
        float f0 = __expf(m0 - ms), f1 = __expf(m1 - ms);
        float lt = f0 * l0 + f1 * l1;
        int flat = flatLd[tid];
        float hw = (flat >= 0) ? head_w[flat] : 0.f;
        facLd[tid][0] = f1;
        facLd[tid][1] = hw / lt;
        facLd[tid][2] = f0;
    }
    __syncthreads();
    if (w == 1) {
        #pragma unroll
        for (int nt = 0; nt < 4; ++nt) {
            int col = nt * 32 + l32;
            #pragma unroll
            for (int reg = 0; reg < 16; ++reg) {
                int row = (reg & 3) + 8 * (reg >> 2) + 4 * g;
                Obuf[row][col] = O[nt][reg] * facLd[row][0];
            }
        }
    }
    __syncthreads();
    if (w == 0) {
        #pragma unroll
        for (int nt = 0; nt < 4; ++nt) {
            int col = nt * 32 + l32;
            #pragma unroll
            for (int reg = 0; reg < 16; ++reg) {
                int row = (reg & 3) + 8 * (reg >> 2) + 4 * g;
                int flat = flatLd[row];
                if (flat >= 0) {
                    float val = (O[nt][reg] * facLd[row][2] + Obuf[row][col]) * facLd[row][1];
                    ao[(size_t)flat * D + col] = (_Float16)val;
                }
            }
        }
    }
}

// ---------------- output projection: B-only LDS dbuf MFMA GEMM, A direct-to-reg ----------------
__global__ __launch_bounds__(256) void out_mfma(
    const _Float16* __restrict__ A, const _Float16* __restrict__ Bt,
    float* __restrict__ C)
{
    int n0 = blockIdx.x * 64, m0 = blockIdx.y * 64;
    int tid = threadIdx.x, wave = tid >> 6, lane = tid & 63;
    int wm = wave >> 1, wn = wave & 1;
    int l32 = lane & 31, g = lane >> 5;

    __shared__ _Float16 Bs[2][64 * 64];

    const _Float16* aptr = A + (size_t)(m0 + wm * 32 + l32) * 1024;

    auto stageB = [&](int buf, int k0) {
        #pragma unroll
        for (int it = 0; it < 2; ++it) {
            int f = it * 256 + tid;
            int row = f >> 3, c = f & 7;
            int sc = c ^ (row & 7);
            GLOAD_LDS16(Bt + (size_t)(n0 + row) * 1024 + k0 + sc * 8, &Bs[buf][f * 8]);
        }
    };

    floatx16 acc = {};
    int brow = wn * 32 + l32;
    half8 a_cur[4], a_nxt[4];
    #pragma unroll
    for (int ks = 0; ks < 4; ++ks)
        a_cur[ks] = *(const half8*)(aptr + ks * 16 + g * 8);

    auto compute = [&](int buf, half8* a) {
        #pragma unroll
        for (int ks = 0; ks < 4; ++ks) {
            int wchunk = ks * 2 + g;
            half8 bf = *(const half8*)&Bs[buf][brow * 64 + (wchunk ^ (brow & 7)) * 8];
            acc = __builtin_amdgcn_mfma_f32_32x32x16_f16(a[ks], bf, acc, 0, 0, 0);
        }
    };

    stageB(0, 0);
    __syncthreads();
    int buf = 0;
    for (int k0 = 64; k0 < 1024; k0 += 64) {
        stageB(buf ^ 1, k0);
        #pragma unroll
        for (int ks = 0; ks < 4; ++ks)
            a_nxt[ks] = *(const half8*)(aptr + k0 + ks * 16 + g * 8);
        compute(buf, a_cur);
        __syncthreads();
        buf ^= 1;
        #pragma unroll
        for (int ks = 0; ks < 4; ++ks) a_cur[ks] = a_nxt[ks];
    }
    compute(buf, a_cur);

    int col = n0 + wn * 32 + l32;
    #pragma unroll
    for (int reg = 0; reg < 16; ++reg) {
        int row = m0 + wm * 32 + (reg & 3) + 8 * (reg >> 2) + 4 * g;
        C[(size_t)row * 1024 + col] = acc[reg];
    }
}

extern "C" void kernel_launch(void* const* d_in, const int* in_sizes, int n_in,
                              void* d_out, int out_size, void* d_ws, size_t ws_size,
                              hipStream_t stream)
{
    const float* x  = (const float*)d_in[0];
    const float* Wq = (const float*)d_in[1];
    const float* Wk = (const float*)d_in[2];
    const float* Wv = (const float*)d_in[3];
    const float* Wr = (const float*)d_in[4];
    const float* Wo = (const float*)d_in[5];
    const int* head_counts = (const int*)d_in[6];
    float* out = (float*)d_out;

    float* head_w = (float*)d_ws;                 // SK
    float* pbuf   = head_w + SK;                  // S*32
    float* entz   = pbuf + S * 32;                // S*2
    int* head_idx = (int*)(entz + S * 2);         // SK
    int* order    = head_idx + SK;                // H*MAXL
    int* hlen     = order + H * MAXL;             // 32 (pad 64)
    _Float16* xh   = (_Float16*)(hlen + 64);      // S*E
    _Float16* aoh  = xh + (size_t)S * E;          // SK*D
    _Float16* Wqkt = aoh + (size_t)SK * D;        // 3*HD*E
    _Float16* Wot  = Wqkt + (size_t)3 * HD * E;   // 1024*1024
    _Float16* qh   = Wot + (size_t)1024 * 1024;   // CAP*D
    _Float16* kh   = qh + (size_t)CAP * D;        // CAP*D
    _Float16* vT   = kh + (size_t)CAP * D;        // CAP*D

    router_kernel<<<S / 4, 256, 0, stream>>>(x, Wr, head_idx, head_w, pbuf, entz, xh);
    order_conv_kernel<<<33 + 4096, 256, 0, stream>>>(head_idx, head_counts, order, hlen,
                                                     out + (size_t)S * E, pbuf, entz,
                                                     out + (size_t)S * E + H,
                                                     Wq, Wk, Wv, Wo, Wqkt, Wot);
    qkv_mfma<<<dim3(96, 16), 256, 0, stream>>>(xh, Wqkt, order, hlen, head_counts,
                                               qh, kh, vT);
    attn_mfma<<<H * 32, 128, 0, stream>>>(qh, kh, vT, order, hlen, head_w, aoh);
    out_mfma<<<dim3(16, 16), 256, 0, stream>>>(aoh, Wot, out);
}